// Round 5
// baseline (200.470 us; speedup 1.0000x reference)
//
#include <hip/hip_runtime.h>
#include <hip/hip_fp16.h>
#include <cstdint>
#include <cstddef>

#define IDIM 192
#define NSAMP 128
#define NRAYS 16384
#define NVOX (IDIM * IDIM * IDIM)   // 7077888
#define NFUSE (NVOX / 256)          // 27648 fuse blocks
#define NPAIR (NRAYS / 2)           // 8192 sortgen blocks (2 rays each)
#define NBLK1 (NFUSE + NPAIR)       // 35840

__device__ __forceinline__ uint32_t rotl32(uint32_t x, int r) {
    return (x << r) | (x >> (32 - r));
}

// JAX threefry2x32, key (0,1), partitionable path: bits(i) = x0 ^ x1 of TF((0,1),(0,i))
__device__ __forceinline__ uint32_t threefry_bits(uint32_t i) {
    const uint32_t ks0 = 0u;
    const uint32_t ks1 = 1u;
    const uint32_t ks2 = 0x1BD11BDAu ^ ks0 ^ ks1;  // 0x1BD11BDB
    uint32_t x0 = 0u + ks0;
    uint32_t x1 = i + ks1;
#define TF_ROUND(r) { x0 += x1; x1 = rotl32(x1, (r)); x1 ^= x0; }
    TF_ROUND(13) TF_ROUND(15) TF_ROUND(26) TF_ROUND(6)
    x0 += ks1; x1 += ks2 + 1u;
    TF_ROUND(17) TF_ROUND(29) TF_ROUND(16) TF_ROUND(24)
    x0 += ks2; x1 += ks0 + 2u;
    TF_ROUND(13) TF_ROUND(15) TF_ROUND(26) TF_ROUND(6)
    x0 += ks0; x1 += ks1 + 3u;
    TF_ROUND(17) TF_ROUND(29) TF_ROUND(16) TF_ROUND(24)
    x0 += ks1; x1 += ks2 + 4u;
    TF_ROUND(13) TF_ROUND(15) TF_ROUND(26) TF_ROUND(6)
    x0 += ks2; x1 += ks0 + 5u;
#undef TF_ROUND
    return x0 ^ x1;
}

// Combined kernel 1: fuse blocks (memory-bound) interleaved with per-ray
// RNG + rank-sort blocks (VALU-bound). Sortgen blocks sit at b%4==1, b<4*NPAIR.
__global__ __launch_bounds__(256)
void prep_kernel(const float* __restrict__ grid, const float* __restrict__ opacity,
                 const float* __restrict__ x, const float* __restrict__ dvec,
                 __half2* __restrict__ tab, float* __restrict__ sts) {
    __shared__ float sh[256 * 9];
    const int b = blockIdx.x;
    const int t = threadIdx.x;
    const bool is_sort = ((b & 3) == 1) && (b < 4 * NPAIR);

    if (!is_sort) {
        // ---- fuse: tab[v] = half2{sum_c grid[v][c], opacity[v]} ----
        const int sg_before = (b < 4 * NPAIR) ? ((b + 2) >> 2) : NPAIR;
        const int base = (b - sg_before) * 256;
        const float* gp = grid + (size_t)base * 9;
        #pragma unroll
        for (int i = 0; i < 9; ++i) {
            sh[i * 256 + t] = gp[i * 256 + t];
        }
        __syncthreads();
        float s = 0.f;
        #pragma unroll
        for (int c = 0; c < 9; ++c) s += sh[t * 9 + c];
        tab[base + t] = __floats2half2_rn(s, opacity[base + t]);
    } else {
        // ---- sortgen: 2 rays per block, 128 threads each ----
        const int pair = b >> 2;
        const int half = t >> 7;
        const int s = t & 127;
        const int r = pair * 2 + half;

        float* sv = sh;         // [256]
        float* st = sh + 256;   // [256]

        const float ox = x[r * 3 + 0], oy = x[r * 3 + 1], oz = x[r * 3 + 2];
        const float dx = dvec[r * 3 + 0], dy = dvec[r * 3 + 1], dz = dvec[r * 3 + 2];
        const float inv_dx = 1.f / dx, inv_dy = 1.f / dy, inv_dz = 1.f / dz;
        const float INF = 7077888.f;  // 192^3
        const float BMAX = (float)(IDIM - 1);

        float tmin = -INF, tmax = INF;
        {
            float t0 = (0.f - ox) * inv_dx, t1 = (BMAX - ox) * inv_dx;
            tmin = fmaxf(tmin, fminf(t0, t1)); tmax = fminf(tmax, fmaxf(t0, t1));
            t0 = (0.f - oy) * inv_dy; t1 = (BMAX - oy) * inv_dy;
            tmin = fmaxf(tmin, fminf(t0, t1)); tmax = fminf(tmax, fmaxf(t0, t1));
            t0 = (0.f - oz) * inv_dz; t1 = (BMAX - oz) * inv_dz;
            tmin = fmaxf(tmin, fminf(t0, t1)); tmax = fminf(tmax, fmaxf(t0, t1));
        }

        const uint32_t i = (uint32_t)(r * NSAMP + s);
        const uint32_t bits = threefry_bits(i);
        float u = __uint_as_float((bits >> 9) | 0x3f800000u) - 1.0f;
        u = fmaxf(0.f, u);
        const float vi = tmin + u * (tmax - tmin);
        sv[t] = vi;
        __syncthreads();

        // rank = #{j: v_j < v_i} + #{j<i: v_j == v_i}, within own ray's 128
        int rank = 0;
        const float* mybase = sv + half * 128;
        #pragma unroll 4
        for (int j = 0; j < NSAMP; j += 4) {
            const float4 q = *reinterpret_cast<const float4*>(&mybase[j]);
            rank += (q.x < vi) | ((q.x == vi) & (j + 0 < s));
            rank += (q.y < vi) | ((q.y == vi) & (j + 1 < s));
            rank += (q.z < vi) | ((q.z == vi) & (j + 2 < s));
            rank += (q.w < vi) | ((q.w == vi) & (j + 3 < s));
        }
        st[half * 128 + rank] = vi;
        __syncthreads();
        sts[r * NSAMP + s] = st[t];   // coalesced sorted write
    }
}

// Kernel 2: lean gather + composite from pre-sorted samples.
__global__ __launch_bounds__(NSAMP)
void rf2_kernel(const float* __restrict__ x, const float* __restrict__ dvec,
                const __half2* __restrict__ tab, const float* __restrict__ sts,
                float* __restrict__ out) {
    const int r = blockIdx.x;
    const int s = threadIdx.x;

    __shared__ float wtot[2];
    __shared__ float wsum[2];

    const float ts = sts[r * NSAMP + s];
    const float tn = (s < NSAMP - 1) ? sts[r * NSAMP + s + 1] : ts;

    const float ox = x[r * 3 + 0], oy = x[r * 3 + 1], oz = x[r * 3 + 2];
    const float dx = dvec[r * 3 + 0], dy = dvec[r * 3 + 1], dz = dvec[r * 3 + 2];

    // --- trilinear interpolation from fused half2 table (8 x 4B gathers) ---
    float opv = 0.f, hsv = 0.f;
    if (s < NSAMP - 1) {
        const float px = ox + ts * dx;
        const float py = oy + ts * dy;
        const float pz = oz + ts * dz;
        int ix = (int)floorf(px); ix = ix < 0 ? 0 : (ix > IDIM - 2 ? IDIM - 2 : ix);
        int iy = (int)floorf(py); iy = iy < 0 ? 0 : (iy > IDIM - 2 ? IDIM - 2 : iy);
        int iz = (int)floorf(pz); iz = iz < 0 ? 0 : (iz > IDIM - 2 ? IDIM - 2 : iz);
        const float fx = px - (float)ix;
        const float fy = py - (float)iy;
        const float fz = pz - (float)iz;
        const float wx0 = 1.f - fx, wx1 = fx;
        const float wy0 = 1.f - fy, wy1 = fy;
        const float wz0 = 1.f - fz, wz1 = fz;
        const float w000 = wx0 * wy0 * wz0, w001 = wx0 * wy0 * wz1;
        const float w010 = wx0 * wy1 * wz0, w011 = wx0 * wy1 * wz1;
        const float w100 = wx1 * wy0 * wz0, w101 = wx1 * wy0 * wz1;
        const float w110 = wx1 * wy1 * wz0, w111 = wx1 * wy1 * wz1;
        const int SX = IDIM * IDIM, SY = IDIM;
        const int v000 = (ix * IDIM + iy) * IDIM + iz;

        const float2 c000 = __half22float2(tab[v000]);
        const float2 c001 = __half22float2(tab[v000 + 1]);
        const float2 c010 = __half22float2(tab[v000 + SY]);
        const float2 c011 = __half22float2(tab[v000 + SY + 1]);
        const float2 c100 = __half22float2(tab[v000 + SX]);
        const float2 c101 = __half22float2(tab[v000 + SX + 1]);
        const float2 c110 = __half22float2(tab[v000 + SX + SY]);
        const float2 c111 = __half22float2(tab[v000 + SX + SY + 1]);
        hsv = w000 * c000.x + w001 * c001.x + w010 * c010.x + w011 * c011.x +
              w100 * c100.x + w101 * c101.x + w110 * c110.x + w111 * c111.x;
        opv = w000 * c000.y + w001 * c001.y + w010 * c010.y + w011 * c011.y +
              w100 * c100.y + w101 * c101.y + w110 * c110.y + w111 * c111.y;
    }

    // --- compositing: exclusive prefix sum of cur over 127 entries ---
    const float cur = (s < NSAMP - 1) ? (tn - ts) * opv : 0.f;
    float incl = cur;
    #pragma unroll
    for (int off = 1; off < 64; off <<= 1) {
        const float v2 = __shfl_up(incl, off, 64);
        if ((s & 63) >= off) incl += v2;
    }
    if ((s & 63) == 63) wtot[s >> 6] = incl;
    __syncthreads();
    if (s >= 64) incl += wtot[0];
    const float excl = incl - cur;

    float contrib = 0.f;
    if (s < NSAMP - 1) {
        const float color = 1.f / (1.f + __expf(-hsv));
        contrib = __expf(-excl) * (1.f - __expf(-cur)) * color;
    }

    // --- block reduction ---
    #pragma unroll
    for (int off = 32; off > 0; off >>= 1) contrib += __shfl_down(contrib, off, 64);
    if ((s & 63) == 0) wsum[s >> 6] = contrib;
    __syncthreads();
    if (s == 0) out[r] = wsum[0] + wsum[1];
}

extern "C" void kernel_launch(void* const* d_in, const int* in_sizes, int n_in,
                              void* d_out, int out_size, void* d_ws, size_t ws_size,
                              hipStream_t stream) {
    const float* x       = (const float*)d_in[0];
    const float* d       = (const float*)d_in[1];
    const float* grid    = (const float*)d_in[2];
    const float* opacity = (const float*)d_in[3];
    float* out = (float*)d_out;

    __half2* tab = (__half2*)d_ws;
    float* sts = (float*)((char*)d_ws + (size_t)NVOX * sizeof(__half2));

    prep_kernel<<<NBLK1, 256, 0, stream>>>(grid, opacity, x, d, tab, sts);
    rf2_kernel<<<NRAYS, NSAMP, 0, stream>>>(x, d, tab, sts, out);
}

// Round 6
// 117.239 us; speedup vs baseline: 1.7099x; 1.7099x over previous
//
#include <hip/hip_runtime.h>
#include <hip/hip_fp16.h>
#include <cstdint>
#include <cstddef>

#define IDIM 192
#define NSAMP 128
#define NRAYS 16384
#define NVOX (IDIM * IDIM * IDIM)   // 7077888

// y-pair table entry (8B aligned):
//   .x = half2{gsum, opac}(x, y,   z)
//   .y = half2{gsum, opac}(x, y+1, z)     (= voxel v + 192)
// Per sample the 8 trilinear corners come from 4 entry loads:
//   e00=v000, e01=v000+1 (z+1), e10=v000+SX (x+1), e11=v000+SX+1
// -> 2 (x)-tubes, z/z+1 adjacent in-line: ~2.25 cache lines per sample.

__device__ __forceinline__ uint32_t rotl32(uint32_t x, int r) {
    return (x << r) | (x >> (32 - r));
}

// JAX threefry2x32, key (0,1), partitionable path: bits(i) = x0 ^ x1 of TF((0,1),(0,i))
__device__ __forceinline__ uint32_t threefry_bits(uint32_t i) {
    const uint32_t ks0 = 0u;
    const uint32_t ks1 = 1u;
    const uint32_t ks2 = 0x1BD11BDAu ^ ks0 ^ ks1;  // 0x1BD11BDB
    uint32_t x0 = 0u + ks0;
    uint32_t x1 = i + ks1;
#define TF_ROUND(r) { x0 += x1; x1 = rotl32(x1, (r)); x1 ^= x0; }
    TF_ROUND(13) TF_ROUND(15) TF_ROUND(26) TF_ROUND(6)
    x0 += ks1; x1 += ks2 + 1u;
    TF_ROUND(17) TF_ROUND(29) TF_ROUND(16) TF_ROUND(24)
    x0 += ks2; x1 += ks0 + 2u;
    TF_ROUND(13) TF_ROUND(15) TF_ROUND(26) TF_ROUND(6)
    x0 += ks0; x1 += ks1 + 3u;
    TF_ROUND(17) TF_ROUND(29) TF_ROUND(16) TF_ROUND(24)
    x0 += ks1; x1 += ks2 + 4u;
    TF_ROUND(13) TF_ROUND(15) TF_ROUND(26) TF_ROUND(6)
    x0 += ks2; x1 += ks0 + 5u;
#undef TF_ROUND
    return x0 ^ x1;
}

// fuse: compute {gsum, opac}(v) once, store it into entry[v].lo and entry[v-192].hi.
// Both stores are coalesced streams; lines get fully populated by temporally
// adjacent blocks (192/256 block offset) so L2 merges before writeback.
__global__ __launch_bounds__(256)
void fuse_kernel(const float* __restrict__ grid, const float* __restrict__ opacity,
                 uint32_t* __restrict__ tb /* = (uint32_t*)uint2-table */) {
    __shared__ float sh[256 * 9];
    const int t = threadIdx.x;
    const int base = blockIdx.x * 256;
    const float* gp = grid + (size_t)base * 9;
    #pragma unroll
    for (int i = 0; i < 9; ++i) {
        sh[i * 256 + t] = gp[i * 256 + t];
    }
    __syncthreads();
    float s = 0.f;
    #pragma unroll
    for (int c = 0; c < 9; ++c) s += sh[t * 9 + c];
    const int v = base + t;
    const __half2 go = __floats2half2_rn(s, opacity[v]);
    const uint32_t bits = *reinterpret_cast<const uint32_t*>(&go);
    tb[2 * v] = bits;                               // entry v   .lo  (y)
    if (v >= IDIM) tb[2 * (v - IDIM) + 1] = bits;   // entry v-192 .hi (y+1)
}

__global__ __launch_bounds__(NSAMP)
void rf_kernel(const float* __restrict__ x, const float* __restrict__ d,
               const uint2* __restrict__ tabp, float* __restrict__ out) {
    const int r = blockIdx.x;
    const int s = threadIdx.x;

    __shared__ float sv[NSAMP];   // unsorted samples
    __shared__ float st[NSAMP];   // sorted samples
    __shared__ float wtot[2];
    __shared__ float wsum[2];

    // --- ray setup (broadcast loads) ---
    const float ox = x[r * 3 + 0], oy = x[r * 3 + 1], oz = x[r * 3 + 2];
    const float dx = d[r * 3 + 0], dy = d[r * 3 + 1], dz = d[r * 3 + 2];
    const float inv_dx = 1.f / dx, inv_dy = 1.f / dy, inv_dz = 1.f / dz;
    const float INF = 7077888.f;  // 192^3
    const float BMAX = (float)(IDIM - 1);

    float tmin = -INF, tmax = INF;
    {
        float t0 = (0.f - ox) * inv_dx, t1 = (BMAX - ox) * inv_dx;
        tmin = fmaxf(tmin, fminf(t0, t1)); tmax = fminf(tmax, fmaxf(t0, t1));
        t0 = (0.f - oy) * inv_dy; t1 = (BMAX - oy) * inv_dy;
        tmin = fmaxf(tmin, fminf(t0, t1)); tmax = fminf(tmax, fmaxf(t0, t1));
        t0 = (0.f - oz) * inv_dz; t1 = (BMAX - oz) * inv_dz;
        tmin = fmaxf(tmin, fminf(t0, t1)); tmax = fminf(tmax, fmaxf(t0, t1));
    }

    // --- JAX-exact uniform sample (partitionable threefry) ---
    const uint32_t i = (uint32_t)(r * NSAMP + s);
    const uint32_t bits = threefry_bits(i);
    float u = __uint_as_float((bits >> 9) | 0x3f800000u) - 1.0f;
    u = fmaxf(0.f, u);
    const float vi = tmin + u * (tmax - tmin);
    sv[s] = vi;
    __syncthreads();

    // --- rank sort: rank = #{j: v_j < v_i} + #{j<i: v_j == v_i} ---
    int rank = 0;
    #pragma unroll 4
    for (int j = 0; j < NSAMP; j += 4) {
        const float4 q = *reinterpret_cast<const float4*>(&sv[j]);
        rank += (q.x < vi) | ((q.x == vi) & (j + 0 < s));
        rank += (q.y < vi) | ((q.y == vi) & (j + 1 < s));
        rank += (q.z < vi) | ((q.z == vi) & (j + 2 < s));
        rank += (q.w < vi) | ((q.w == vi) & (j + 3 < s));
    }
    st[rank] = vi;
    __syncthreads();
    const float ts = st[s];
    const float tn = (s < NSAMP - 1) ? st[s + 1] : ts;

    // --- trilinear interpolation from y-pair table: 4 aligned 8B loads ---
    float opv = 0.f, hsv = 0.f;
    if (s < NSAMP - 1) {
        const float px = ox + ts * dx;
        const float py = oy + ts * dy;
        const float pz = oz + ts * dz;
        int ix = (int)floorf(px); ix = ix < 0 ? 0 : (ix > IDIM - 2 ? IDIM - 2 : ix);
        int iy = (int)floorf(py); iy = iy < 0 ? 0 : (iy > IDIM - 2 ? IDIM - 2 : iy);
        int iz = (int)floorf(pz); iz = iz < 0 ? 0 : (iz > IDIM - 2 ? IDIM - 2 : iz);
        const float fx = px - (float)ix;
        const float fy = py - (float)iy;
        const float fz = pz - (float)iz;
        const int SX = IDIM * IDIM;
        const int v000 = (ix * IDIM + iy) * IDIM + iz;

        const uint2 e00 = tabp[v000];           // (x, y/y+1, z)
        const uint2 e01 = tabp[v000 + 1];       // (x, y/y+1, z+1)
        const uint2 e10 = tabp[v000 + SX];      // (x+1, y/y+1, z)
        const uint2 e11 = tabp[v000 + SX + 1];  // (x+1, y/y+1, z+1)

        const float2 a00 = __half22float2(*reinterpret_cast<const __half2*>(&e00.x));
        const float2 b00 = __half22float2(*reinterpret_cast<const __half2*>(&e00.y));
        const float2 a01 = __half22float2(*reinterpret_cast<const __half2*>(&e01.x));
        const float2 b01 = __half22float2(*reinterpret_cast<const __half2*>(&e01.y));
        const float2 a10 = __half22float2(*reinterpret_cast<const __half2*>(&e10.x));
        const float2 b10 = __half22float2(*reinterpret_cast<const __half2*>(&e10.y));
        const float2 a11 = __half22float2(*reinterpret_cast<const __half2*>(&e11.x));
        const float2 b11 = __half22float2(*reinterpret_cast<const __half2*>(&e11.y));

        // y-lerp each (x,z) pair
        const float wy0 = 1.f - fy, wy1 = fy;
        const float g00 = wy0 * a00.x + wy1 * b00.x, o00 = wy0 * a00.y + wy1 * b00.y;
        const float g01 = wy0 * a01.x + wy1 * b01.x, o01 = wy0 * a01.y + wy1 * b01.y;
        const float g10 = wy0 * a10.x + wy1 * b10.x, o10 = wy0 * a10.y + wy1 * b10.y;
        const float g11 = wy0 * a11.x + wy1 * b11.x, o11 = wy0 * a11.y + wy1 * b11.y;
        // z-lerp then x-lerp
        const float wz0 = 1.f - fz, wz1 = fz;
        const float g0 = wz0 * g00 + wz1 * g01, o0 = wz0 * o00 + wz1 * o01;
        const float g1 = wz0 * g10 + wz1 * g11, o1 = wz0 * o10 + wz1 * o11;
        const float wx0 = 1.f - fx, wx1 = fx;
        hsv = wx0 * g0 + wx1 * g1;
        opv = wx0 * o0 + wx1 * o1;
    }

    // --- compositing: exclusive prefix sum of cur over 127 entries ---
    const float cur = (s < NSAMP - 1) ? (tn - ts) * opv : 0.f;
    float incl = cur;
    #pragma unroll
    for (int off = 1; off < 64; off <<= 1) {
        const float v2 = __shfl_up(incl, off, 64);
        if ((s & 63) >= off) incl += v2;
    }
    if ((s & 63) == 63) wtot[s >> 6] = incl;
    __syncthreads();
    if (s >= 64) incl += wtot[0];
    const float excl = incl - cur;

    float contrib = 0.f;
    if (s < NSAMP - 1) {
        const float color = 1.f / (1.f + __expf(-hsv));
        contrib = __expf(-excl) * (1.f - __expf(-cur)) * color;
    }

    // --- block reduction ---
    #pragma unroll
    for (int off = 32; off > 0; off >>= 1) contrib += __shfl_down(contrib, off, 64);
    if ((s & 63) == 0) wsum[s >> 6] = contrib;
    __syncthreads();
    if (s == 0) out[r] = wsum[0] + wsum[1];
}

extern "C" void kernel_launch(void* const* d_in, const int* in_sizes, int n_in,
                              void* d_out, int out_size, void* d_ws, size_t ws_size,
                              hipStream_t stream) {
    const float* x       = (const float*)d_in[0];
    const float* d       = (const float*)d_in[1];
    const float* grid    = (const float*)d_in[2];
    const float* opacity = (const float*)d_in[3];
    float* out = (float*)d_out;

    fuse_kernel<<<NVOX / 256, 256, 0, stream>>>(grid, opacity, (uint32_t*)d_ws);
    rf_kernel<<<NRAYS, NSAMP, 0, stream>>>(x, d, (const uint2*)d_ws, out);
}

// Round 7
// 107.355 us; speedup vs baseline: 1.8674x; 1.0921x over previous
//
#include <hip/hip_runtime.h>
#include <hip/hip_fp16.h>
#include <cstdint>
#include <cstddef>

#define IDIM 192
#define NSAMP 128
#define NRAYS 16384
#define NVOX (IDIM * IDIM * IDIM)   // 7077888

// Brick layout: 2x2x4 voxels = 16 entries x 4B = exactly one 64B cache line.
//   idx(x,y,z) = f(x) + g(y) + h(z)
//   f(x) = (x>>1)*73728 + (x&1)*8      (73728 = 96*48*16)
//   g(y) = (y>>1)*768   + (y&1)*4      (768   = 48*16)
//   h(z) = (z>>2)*16    + (z&3)
// 8 trilinear corners touch E[1.5*1.5*1.25] = 2.81 lines/sample (vs 4.25 z-major).

__device__ __forceinline__ uint32_t rotl32(uint32_t x, int r) {
    return (x << r) | (x >> (32 - r));
}

// JAX threefry2x32, key (0,1), partitionable path: bits(i) = x0 ^ x1 of TF((0,1),(0,i))
__device__ __forceinline__ uint32_t threefry_bits(uint32_t i) {
    const uint32_t ks0 = 0u;
    const uint32_t ks1 = 1u;
    const uint32_t ks2 = 0x1BD11BDAu ^ ks0 ^ ks1;  // 0x1BD11BDB
    uint32_t x0 = 0u + ks0;
    uint32_t x1 = i + ks1;
#define TF_ROUND(r) { x0 += x1; x1 = rotl32(x1, (r)); x1 ^= x0; }
    TF_ROUND(13) TF_ROUND(15) TF_ROUND(26) TF_ROUND(6)
    x0 += ks1; x1 += ks2 + 1u;
    TF_ROUND(17) TF_ROUND(29) TF_ROUND(16) TF_ROUND(24)
    x0 += ks2; x1 += ks0 + 2u;
    TF_ROUND(13) TF_ROUND(15) TF_ROUND(26) TF_ROUND(6)
    x0 += ks0; x1 += ks1 + 3u;
    TF_ROUND(17) TF_ROUND(29) TF_ROUND(16) TF_ROUND(24)
    x0 += ks1; x1 += ks2 + 4u;
    TF_ROUND(13) TF_ROUND(15) TF_ROUND(26) TF_ROUND(6)
    x0 += ks2; x1 += ks0 + 5u;
#undef TF_ROUND
    return x0 ^ x1;
}

// fuse: coalesced grid/opacity reads; brick-scattered 4B table writes
// (partial 64B lines merge in L2 across temporally-close blocks).
__global__ __launch_bounds__(256)
void fuse_kernel(const float* __restrict__ grid, const float* __restrict__ opacity,
                 __half2* __restrict__ tab) {
    __shared__ float sh[256 * 9];
    const int t = threadIdx.x;
    const int base = blockIdx.x * 256;
    const float* gp = grid + (size_t)base * 9;
    #pragma unroll
    for (int i = 0; i < 9; ++i) {
        sh[i * 256 + t] = gp[i * 256 + t];
    }
    __syncthreads();
    float s = 0.f;
    #pragma unroll
    for (int c = 0; c < 9; ++c) s += sh[t * 9 + c];
    const int v = base + t;
    // decode z-major (x,y,z)
    const int xq = v / (IDIM * IDIM);
    const int rem = v - xq * (IDIM * IDIM);
    const int yq = rem / IDIM;
    const int zq = rem - yq * IDIM;
    const int idx = (xq >> 1) * 73728 + ((xq & 1) << 3)
                  + (yq >> 1) * 768   + ((yq & 1) << 2)
                  + (zq >> 2) * 16    + (zq & 3);
    tab[idx] = __floats2half2_rn(s, opacity[v]);
}

__global__ __launch_bounds__(NSAMP)
void rf_kernel(const float* __restrict__ x, const float* __restrict__ d,
               const __half2* __restrict__ tab, float* __restrict__ out) {
    const int r = blockIdx.x;
    const int s = threadIdx.x;

    __shared__ float sv[NSAMP];   // unsorted samples
    __shared__ float st[NSAMP];   // sorted samples
    __shared__ float wtot[2];
    __shared__ float wsum[2];

    // --- ray setup (broadcast loads) ---
    const float ox = x[r * 3 + 0], oy = x[r * 3 + 1], oz = x[r * 3 + 2];
    const float dx = d[r * 3 + 0], dy = d[r * 3 + 1], dz = d[r * 3 + 2];
    const float inv_dx = 1.f / dx, inv_dy = 1.f / dy, inv_dz = 1.f / dz;
    const float INF = 7077888.f;  // 192^3
    const float BMAX = (float)(IDIM - 1);

    float tmin = -INF, tmax = INF;
    {
        float t0 = (0.f - ox) * inv_dx, t1 = (BMAX - ox) * inv_dx;
        tmin = fmaxf(tmin, fminf(t0, t1)); tmax = fminf(tmax, fmaxf(t0, t1));
        t0 = (0.f - oy) * inv_dy; t1 = (BMAX - oy) * inv_dy;
        tmin = fmaxf(tmin, fminf(t0, t1)); tmax = fminf(tmax, fmaxf(t0, t1));
        t0 = (0.f - oz) * inv_dz; t1 = (BMAX - oz) * inv_dz;
        tmin = fmaxf(tmin, fminf(t0, t1)); tmax = fminf(tmax, fmaxf(t0, t1));
    }

    // --- JAX-exact uniform sample (partitionable threefry) ---
    const uint32_t i = (uint32_t)(r * NSAMP + s);
    const uint32_t bits = threefry_bits(i);
    float u = __uint_as_float((bits >> 9) | 0x3f800000u) - 1.0f;
    u = fmaxf(0.f, u);
    const float vi = tmin + u * (tmax - tmin);
    sv[s] = vi;
    __syncthreads();

    // --- rank sort: rank = #{j: v_j < v_i} + #{j<i: v_j == v_i} ---
    int rank = 0;
    #pragma unroll 4
    for (int j = 0; j < NSAMP; j += 4) {
        const float4 q = *reinterpret_cast<const float4*>(&sv[j]);
        rank += (q.x < vi) | ((q.x == vi) & (j + 0 < s));
        rank += (q.y < vi) | ((q.y == vi) & (j + 1 < s));
        rank += (q.z < vi) | ((q.z == vi) & (j + 2 < s));
        rank += (q.w < vi) | ((q.w == vi) & (j + 3 < s));
    }
    st[rank] = vi;
    __syncthreads();
    const float ts = st[s];
    const float tn = (s < NSAMP - 1) ? st[s + 1] : ts;

    // --- trilinear interpolation from bricked half2 table (8 x 4B gathers) ---
    float opv = 0.f, hsv = 0.f;
    if (s < NSAMP - 1) {
        const float px = ox + ts * dx;
        const float py = oy + ts * dy;
        const float pz = oz + ts * dz;
        int ix = (int)floorf(px); ix = ix < 0 ? 0 : (ix > IDIM - 2 ? IDIM - 2 : ix);
        int iy = (int)floorf(py); iy = iy < 0 ? 0 : (iy > IDIM - 2 ? IDIM - 2 : iy);
        int iz = (int)floorf(pz); iz = iz < 0 ? 0 : (iz > IDIM - 2 ? IDIM - 2 : iz);
        const float fx = px - (float)ix;
        const float fy = py - (float)iy;
        const float fz = pz - (float)iz;
        const float wx0 = 1.f - fx, wx1 = fx;
        const float wy0 = 1.f - fy, wy1 = fy;
        const float wz0 = 1.f - fz, wz1 = fz;
        const float w000 = wx0 * wy0 * wz0, w001 = wx0 * wy0 * wz1;
        const float w010 = wx0 * wy1 * wz0, w011 = wx0 * wy1 * wz1;
        const float w100 = wx1 * wy0 * wz0, w101 = wx1 * wy0 * wz1;
        const float w110 = wx1 * wy1 * wz0, w111 = wx1 * wy1 * wz1;

        // brick address components
        const int f0 = (ix >> 1) * 73728 + ((ix & 1) << 3);
        const int f1 = ((ix + 1) >> 1) * 73728 + (((ix + 1) & 1) << 3);
        const int g0 = (iy >> 1) * 768 + ((iy & 1) << 2);
        const int g1 = ((iy + 1) >> 1) * 768 + (((iy + 1) & 1) << 2);
        const int h0 = (iz >> 2) * 16 + (iz & 3);
        const int h1 = ((iz + 1) >> 2) * 16 + ((iz + 1) & 3);

        const float2 c000 = __half22float2(tab[f0 + g0 + h0]);
        const float2 c001 = __half22float2(tab[f0 + g0 + h1]);
        const float2 c010 = __half22float2(tab[f0 + g1 + h0]);
        const float2 c011 = __half22float2(tab[f0 + g1 + h1]);
        const float2 c100 = __half22float2(tab[f1 + g0 + h0]);
        const float2 c101 = __half22float2(tab[f1 + g0 + h1]);
        const float2 c110 = __half22float2(tab[f1 + g1 + h0]);
        const float2 c111 = __half22float2(tab[f1 + g1 + h1]);
        hsv = w000 * c000.x + w001 * c001.x + w010 * c010.x + w011 * c011.x +
              w100 * c100.x + w101 * c101.x + w110 * c110.x + w111 * c111.x;
        opv = w000 * c000.y + w001 * c001.y + w010 * c010.y + w011 * c011.y +
              w100 * c100.y + w101 * c101.y + w110 * c110.y + w111 * c111.y;
    }

    // --- compositing: exclusive prefix sum of cur over 127 entries ---
    const float cur = (s < NSAMP - 1) ? (tn - ts) * opv : 0.f;
    float incl = cur;
    #pragma unroll
    for (int off = 1; off < 64; off <<= 1) {
        const float v2 = __shfl_up(incl, off, 64);
        if ((s & 63) >= off) incl += v2;
    }
    if ((s & 63) == 63) wtot[s >> 6] = incl;
    __syncthreads();
    if (s >= 64) incl += wtot[0];
    const float excl = incl - cur;

    float contrib = 0.f;
    if (s < NSAMP - 1) {
        const float color = 1.f / (1.f + __expf(-hsv));
        contrib = __expf(-excl) * (1.f - __expf(-cur)) * color;
    }

    // --- block reduction ---
    #pragma unroll
    for (int off = 32; off > 0; off >>= 1) contrib += __shfl_down(contrib, off, 64);
    if ((s & 63) == 0) wsum[s >> 6] = contrib;
    __syncthreads();
    if (s == 0) out[r] = wsum[0] + wsum[1];
}

extern "C" void kernel_launch(void* const* d_in, const int* in_sizes, int n_in,
                              void* d_out, int out_size, void* d_ws, size_t ws_size,
                              hipStream_t stream) {
    const float* x       = (const float*)d_in[0];
    const float* d       = (const float*)d_in[1];
    const float* grid    = (const float*)d_in[2];
    const float* opacity = (const float*)d_in[3];
    float* out = (float*)d_out;

    fuse_kernel<<<NVOX / 256, 256, 0, stream>>>(grid, opacity, (__half2*)d_ws);
    rf_kernel<<<NRAYS, NSAMP, 0, stream>>>(x, d, (const __half2*)d_ws, out);
}

// Round 8
// 100.171 us; speedup vs baseline: 2.0013x; 1.0717x over previous
//
#include <hip/hip_runtime.h>
#include <hip/hip_fp16.h>
#include <cstdint>
#include <cstddef>

#define IDIM 192
#define NSAMP 128
#define NRAYS 16384
#define NVOX (IDIM * IDIM * IDIM)   // 7077888

// Brick layout: 2x2x4 voxels = 16 entries x 4B = exactly one 64B cache line.
//   idx(x,y,z) = f(x) + g(y) + h(z)
//   f(x) = (x>>1)*73728 + (x&1)*8      (73728 = 96*48*16)
//   g(y) = (y>>1)*768   + (y&1)*4      (768   = 48*16)
//   h(z) = (z>>2)*16    + (z&3)

__device__ __forceinline__ uint32_t rotl32(uint32_t x, int r) {
    return (x << r) | (x >> (32 - r));
}

// JAX threefry2x32, key (0,1), partitionable path: bits(i) = x0 ^ x1 of TF((0,1),(0,i))
__device__ __forceinline__ uint32_t threefry_bits(uint32_t i) {
    const uint32_t ks0 = 0u;
    const uint32_t ks1 = 1u;
    const uint32_t ks2 = 0x1BD11BDAu ^ ks0 ^ ks1;  // 0x1BD11BDB
    uint32_t x0 = 0u + ks0;
    uint32_t x1 = i + ks1;
#define TF_ROUND(r) { x0 += x1; x1 = rotl32(x1, (r)); x1 ^= x0; }
    TF_ROUND(13) TF_ROUND(15) TF_ROUND(26) TF_ROUND(6)
    x0 += ks1; x1 += ks2 + 1u;
    TF_ROUND(17) TF_ROUND(29) TF_ROUND(16) TF_ROUND(24)
    x0 += ks2; x1 += ks0 + 2u;
    TF_ROUND(13) TF_ROUND(15) TF_ROUND(26) TF_ROUND(6)
    x0 += ks0; x1 += ks1 + 3u;
    TF_ROUND(17) TF_ROUND(29) TF_ROUND(16) TF_ROUND(24)
    x0 += ks1; x1 += ks2 + 4u;
    TF_ROUND(13) TF_ROUND(15) TF_ROUND(26) TF_ROUND(6)
    x0 += ks2; x1 += ks0 + 5u;
#undef TF_ROUND
    return x0 ^ x1;
}

// fuse: coalesced grid/opacity reads; brick-scattered 4B table writes
__global__ __launch_bounds__(256)
void fuse_kernel(const float* __restrict__ grid, const float* __restrict__ opacity,
                 __half2* __restrict__ tab) {
    __shared__ float sh[256 * 9];
    const int t = threadIdx.x;
    const int base = blockIdx.x * 256;
    const float* gp = grid + (size_t)base * 9;
    #pragma unroll
    for (int i = 0; i < 9; ++i) {
        sh[i * 256 + t] = gp[i * 256 + t];
    }
    __syncthreads();
    float s = 0.f;
    #pragma unroll
    for (int c = 0; c < 9; ++c) s += sh[t * 9 + c];
    const int v = base + t;
    const int xq = v / (IDIM * IDIM);
    const int rem = v - xq * (IDIM * IDIM);
    const int yq = rem / IDIM;
    const int zq = rem - yq * IDIM;
    const int idx = (xq >> 1) * 73728 + ((xq & 1) << 3)
                  + (yq >> 1) * 768   + ((yq & 1) << 2)
                  + (zq >> 2) * 16    + (zq & 3);
    tab[idx] = __floats2half2_rn(s, opacity[v]);
}

// One ray per WAVE; 2 waves (rays) per 128-thread block; no __syncthreads.
// Round 1 composites sorted samples 0..63; round 2 (64..126) is skipped
// when transmittance is already < e^-15 (wave-uniform branch).
__global__ __launch_bounds__(128)
void rf_kernel(const float* __restrict__ x, const float* __restrict__ d,
               const __half2* __restrict__ tab, float* __restrict__ out) {
    const int wave = threadIdx.x >> 6;
    const int lane = threadIdx.x & 63;
    const int r = blockIdx.x * 2 + wave;

    __shared__ __align__(16) float sv[2][NSAMP];  // unsorted, per wave
    __shared__ float st[2][NSAMP];                // sorted, per wave
    float* svw = sv[wave];
    float* stw = st[wave];

    // --- ray setup ---
    const float ox = x[r * 3 + 0], oy = x[r * 3 + 1], oz = x[r * 3 + 2];
    const float dx = d[r * 3 + 0], dy = d[r * 3 + 1], dz = d[r * 3 + 2];
    const float inv_dx = 1.f / dx, inv_dy = 1.f / dy, inv_dz = 1.f / dz;
    const float INF = 7077888.f;  // 192^3
    const float BMAX = (float)(IDIM - 1);

    float tmin = -INF, tmax = INF;
    {
        float t0 = (0.f - ox) * inv_dx, t1 = (BMAX - ox) * inv_dx;
        tmin = fmaxf(tmin, fminf(t0, t1)); tmax = fminf(tmax, fmaxf(t0, t1));
        t0 = (0.f - oy) * inv_dy; t1 = (BMAX - oy) * inv_dy;
        tmin = fmaxf(tmin, fminf(t0, t1)); tmax = fminf(tmax, fmaxf(t0, t1));
        t0 = (0.f - oz) * inv_dz; t1 = (BMAX - oz) * inv_dz;
        tmin = fmaxf(tmin, fminf(t0, t1)); tmax = fminf(tmax, fmaxf(t0, t1));
    }

    // --- JAX-exact uniforms: this thread owns samples (lane) and (lane+64) ---
    const uint32_t i0 = (uint32_t)(r * NSAMP + lane);
    const uint32_t b0 = threefry_bits(i0);
    const uint32_t b1 = threefry_bits(i0 + 64u);
    float u0 = __uint_as_float((b0 >> 9) | 0x3f800000u) - 1.0f;
    float u1 = __uint_as_float((b1 >> 9) | 0x3f800000u) - 1.0f;
    u0 = fmaxf(0.f, u0);
    u1 = fmaxf(0.f, u1);
    const float v0 = tmin + u0 * (tmax - tmin);
    const float v1 = tmin + u1 * (tmax - tmin);
    svw[lane] = v0;
    svw[lane + 64] = v1;
    // wave-synchronous LDS: same-wave write->read, no barrier needed

    // --- rank sort (2 ranks/thread, broadcast float4 reads) ---
    int r0 = 0, r1 = 0;
    const int s1i = lane + 64;
    #pragma unroll 4
    for (int j = 0; j < NSAMP; j += 4) {
        const float4 q = *reinterpret_cast<const float4*>(&svw[j]);
        r0 += (q.x < v0) | ((q.x == v0) & (j + 0 < lane));
        r0 += (q.y < v0) | ((q.y == v0) & (j + 1 < lane));
        r0 += (q.z < v0) | ((q.z == v0) & (j + 2 < lane));
        r0 += (q.w < v0) | ((q.w == v0) & (j + 3 < lane));
        r1 += (q.x < v1) | ((q.x == v1) & (j + 0 < s1i));
        r1 += (q.y < v1) | ((q.y == v1) & (j + 1 < s1i));
        r1 += (q.z < v1) | ((q.z == v1) & (j + 2 < s1i));
        r1 += (q.w < v1) | ((q.w == v1) & (j + 3 < s1i));
    }
    stw[r0] = v0;
    stw[r1] = v1;

    // trilinear gather from bricked table
    auto sample_tab = [&](float tpar, float& hsv, float& opv) {
        const float px = ox + tpar * dx;
        const float py = oy + tpar * dy;
        const float pz = oz + tpar * dz;
        int ix = (int)floorf(px); ix = ix < 0 ? 0 : (ix > IDIM - 2 ? IDIM - 2 : ix);
        int iy = (int)floorf(py); iy = iy < 0 ? 0 : (iy > IDIM - 2 ? IDIM - 2 : iy);
        int iz = (int)floorf(pz); iz = iz < 0 ? 0 : (iz > IDIM - 2 ? IDIM - 2 : iz);
        const float fx = px - (float)ix;
        const float fy = py - (float)iy;
        const float fz = pz - (float)iz;
        const float wx0 = 1.f - fx, wx1 = fx;
        const float wy0 = 1.f - fy, wy1 = fy;
        const float wz0 = 1.f - fz, wz1 = fz;
        const float w000 = wx0 * wy0 * wz0, w001 = wx0 * wy0 * wz1;
        const float w010 = wx0 * wy1 * wz0, w011 = wx0 * wy1 * wz1;
        const float w100 = wx1 * wy0 * wz0, w101 = wx1 * wy0 * wz1;
        const float w110 = wx1 * wy1 * wz0, w111 = wx1 * wy1 * wz1;
        const int f0 = (ix >> 1) * 73728 + ((ix & 1) << 3);
        const int f1 = ((ix + 1) >> 1) * 73728 + (((ix + 1) & 1) << 3);
        const int g0 = (iy >> 1) * 768 + ((iy & 1) << 2);
        const int g1 = ((iy + 1) >> 1) * 768 + (((iy + 1) & 1) << 2);
        const int h0 = (iz >> 2) * 16 + (iz & 3);
        const int h1 = ((iz + 1) >> 2) * 16 + ((iz + 1) & 3);
        const float2 c000 = __half22float2(tab[f0 + g0 + h0]);
        const float2 c001 = __half22float2(tab[f0 + g0 + h1]);
        const float2 c010 = __half22float2(tab[f0 + g1 + h0]);
        const float2 c011 = __half22float2(tab[f0 + g1 + h1]);
        const float2 c100 = __half22float2(tab[f1 + g0 + h0]);
        const float2 c101 = __half22float2(tab[f1 + g0 + h1]);
        const float2 c110 = __half22float2(tab[f1 + g1 + h0]);
        const float2 c111 = __half22float2(tab[f1 + g1 + h1]);
        hsv = w000 * c000.x + w001 * c001.x + w010 * c010.x + w011 * c011.x +
              w100 * c100.x + w101 * c101.x + w110 * c110.x + w111 * c111.x;
        opv = w000 * c000.y + w001 * c001.y + w010 * c010.y + w011 * c011.y +
              w100 * c100.y + w101 * c101.y + w110 * c110.y + w111 * c111.y;
    };

    // ---- Round 1: samples 0..63 (all lanes active) ----
    const float ts = stw[lane];
    const float tn = stw[lane + 1];
    float hsv, opv;
    sample_tab(ts, hsv, opv);
    const float cur = (tn - ts) * opv;

    float incl = cur;
    #pragma unroll
    for (int off = 1; off < 64; off <<= 1) {
        const float tmp = __shfl_up(incl, off);
        if (lane >= off) incl += tmp;
    }
    const float excl = incl - cur;
    const float color = 1.f / (1.f + __expf(-hsv));
    float contrib = __expf(-excl) * (1.f - __expf(-cur)) * color;

    float red = contrib;
    #pragma unroll
    for (int off = 32; off > 0; off >>= 1) red += __shfl_down(red, off);
    float total = red;  // valid on lane 0

    const float cum64 = __shfl(incl, 63);

    // ---- Round 2: samples 64..126, only if transmittance still matters ----
    if (cum64 < 15.f) {
        const bool act = lane < 63;
        const int s2 = lane + 64;
        const float ts2 = stw[act ? s2 : 126];
        const float tn2 = stw[act ? s2 + 1 : 127];
        float hsv2, opv2;
        sample_tab(ts2, hsv2, opv2);
        const float cur2 = act ? (tn2 - ts2) * opv2 : 0.f;

        float incl2 = cur2;
        #pragma unroll
        for (int off = 1; off < 64; off <<= 1) {
            const float tmp = __shfl_up(incl2, off);
            if (lane >= off) incl2 += tmp;
        }
        const float excl2 = cum64 + (incl2 - cur2);
        const float color2 = 1.f / (1.f + __expf(-hsv2));
        float c2 = act ? __expf(-excl2) * (1.f - __expf(-cur2)) * color2 : 0.f;
        #pragma unroll
        for (int off = 32; off > 0; off >>= 1) c2 += __shfl_down(c2, off);
        total += c2;
    }

    if (lane == 0) out[r] = total;
}

extern "C" void kernel_launch(void* const* d_in, const int* in_sizes, int n_in,
                              void* d_out, int out_size, void* d_ws, size_t ws_size,
                              hipStream_t stream) {
    const float* x       = (const float*)d_in[0];
    const float* d       = (const float*)d_in[1];
    const float* grid    = (const float*)d_in[2];
    const float* opacity = (const float*)d_in[3];
    float* out = (float*)d_out;

    fuse_kernel<<<NVOX / 256, 256, 0, stream>>>(grid, opacity, (__half2*)d_ws);
    rf_kernel<<<NRAYS / 2, 128, 0, stream>>>(x, d, (const __half2*)d_ws, out);
}